// Round 13
// baseline (1027.085 us; speedup 1.0000x reference)
//
#include <hip/hip_runtime.h>
#include <hip/hip_bf16.h>
#include <math.h>

#define NTOK   8192      // B*S tokens
#define NEXP   64
#define EMBD   1024
#define MLPD   2048
#define TOPK   2
#define NFLAT  (NTOK * TOPK)
#define BKD    32        // K tile
#define MAXCH  8         // max m-chunks of 128 (mean Me=256)

typedef __attribute__((ext_vector_type(4)))  float  f32x4;
typedef __attribute__((ext_vector_type(2)))  float  f32x2;
typedef __attribute__((ext_vector_type(16))) float  f32x16;
typedef __attribute__((ext_vector_type(8)))  __bf16 bf16x8;
typedef __attribute__((ext_vector_type(4)))  __bf16 bf16x4;

// global -> LDS direct (16B/lane). LDS dest = wave-uniform base + lane*16.
__device__ __forceinline__ void gl16(const void* g, void* lds_base) {
  __builtin_amdgcn_global_load_lds(
      (const __attribute__((address_space(1))) unsigned int*)g,
      (__attribute__((address_space(3))) unsigned int*)lds_base, 16, 0, 0);
}

// ---------------- workspace layout (bytes) ----------------
#define OFF_COUNTS 0
#define OFF_BASE   256
#define OFF_RUN    512
#define OFF_EFLAT  1024
#define OFF_WFLAT  (1024 + 65536)
#define OFF_ROWTOK (1024 + 2 * 65536)
#define OFF_F2R    (1024 + 3 * 65536)
#define OFF_INTER  (1024 + 4 * 65536)                       // bf16 [16384][2048]
#define OFF_OS     (OFF_INTER + (size_t)NFLAT * MLPD * 2)   // out_sorted
#define OFF_XB     OFF_OS   // xb (bf16 x) aliases os: xb dead before gemm2 writes os
#define NEED_F32   (OFF_OS + (size_t)NFLAT * EMBD * 4)

// ---------------- x -> bf16 convert ----------------
__global__ __launch_bounds__(256) void cvt_x_k(const float* __restrict__ x,
                                               __bf16* __restrict__ xb) {
  size_t i = ((size_t)blockIdx.x * 256 + threadIdx.x) * 8;
  f32x4 f0 = *(const f32x4*)(x + i);
  f32x4 f1 = *(const f32x4*)(x + i + 4);
  bf16x8 v;
  #pragma unroll
  for (int q = 0; q < 4; ++q) { v[q] = (__bf16)f0[q]; v[4 + q] = (__bf16)f1[q]; }
  *(bf16x8*)(xb + i) = v;
}

// ---------------- router: logits + top-2 + softmax ----------------
__global__ __launch_bounds__(256) void router_topk(
    const float* __restrict__ x, const float* __restrict__ gk,
    int* __restrict__ e_flat, float* __restrict__ w_flat) {
  int t = blockIdx.x * 4 + (threadIdx.x >> 6);
  int l = threadIdx.x & 63;
  const float* xr = x + (size_t)t * EMBD;
  float acc = 0.f;
  #pragma unroll 8
  for (int i = 0; i < EMBD; ++i)
    acc = fmaf(xr[i], gk[i * NEXP + l], acc);
  float m = acc;
  for (int o = 32; o; o >>= 1) m = fmaxf(m, __shfl_xor(m, o));
  unsigned long long b1 = __ballot(acc == m);
  int i1 = __ffsll(b1) - 1;
  float v2 = (l == i1) ? -INFINITY : acc;
  float m2 = v2;
  for (int o = 32; o; o >>= 1) m2 = fmaxf(m2, __shfl_xor(m2, o));
  unsigned long long b2 = __ballot(v2 == m2);
  int i2 = __ffsll(b2) - 1;
  if (l == 0) {
    float e2 = expf(m2 - m);
    float inv = 1.f / (1.f + e2);
    e_flat[2 * t] = i1;  e_flat[2 * t + 1] = i2;
    w_flat[2 * t] = inv; w_flat[2 * t + 1] = e2 * inv;
  }
}

// ---------------- histogram / scan / scatter ----------------
__global__ void hist_k(const int* __restrict__ ef, int* __restrict__ counts) {
  int j = blockIdx.x * 256 + threadIdx.x;
  if (j < NFLAT) atomicAdd(&counts[ef[j]], 1);
}

__global__ void scan_k(const int* __restrict__ counts, int* __restrict__ base) {
  if (threadIdx.x == 0) {
    int s = 0;
    for (int e = 0; e < NEXP; ++e) { base[e] = s; s += counts[e]; }
  }
}

__global__ void scatter_k(const int* __restrict__ ef, const int* __restrict__ base,
                          int* __restrict__ run, int* __restrict__ rowtok,
                          int* __restrict__ f2r) {
  int j = blockIdx.x * 256 + threadIdx.x;
  if (j < NFLAT) {
    int e = ef[j];
    int r = base[e] + atomicAdd(&run[e], 1);
    f2r[j] = r;
    rowtok[r] = j >> 1;
  }
}

// ---------------- grouped GEMM 1: inter = silu(x@w0) * (x@w1) ----------------
// 128m x 64n x 32k; 4 waves 2x2 (wave 64m x 32n); MFMA 32x32x16.
// ring-3 LDS, DEPTH-2 on both streams:
//   A: gl_lds bf16 fragment-major, STAGEA(j+2), 2 gl16/wave.
//   B: reg-staged f32 (2 named sets, LOADB(j+3), 8 b64/wave), cvt->bf16,
//      ds_write to conflict-free layout [mat][koctet][par][col/2] (2-way free).
// One barrier/iter; uniform counted vmcnt(10) (2-iter flight for every load).
__global__ __launch_bounds__(256, 3) void gemm1_k(
    const __bf16* __restrict__ xb, const float* __restrict__ w0,
    const float* __restrict__ w1, const int* __restrict__ counts,
    const int* __restrict__ base, const int* __restrict__ rowtok,
    __hip_bfloat16* __restrict__ inter) {
  // XCD swizzle: swap low-3 bits of x and z -> each expert on one XCD
  int xr_ = blockIdx.x, zr_ = blockIdx.z;
  int xi = (xr_ & ~7) | (zr_ & 7);
  int e  = (zr_ & ~7) | (xr_ & 7);
  int Me = counts[e];
  int mc = blockIdx.y;
  if (mc * 128 >= Me) return;
  int rs = base[e];
  int nb = xi * 64;
  int t = threadIdx.x;
  int wv = t >> 6, l = t & 63;
  int wr = wv >> 1, wc = wv & 1;
  int lo = l & 31, hi = l >> 5;

  __shared__ __bf16 Ax[3][4096];  // 3 x 8KB [g4][kh2][lane64][8]
  __shared__ __bf16 Bx[3][4096];  // 3 x 8KB [bm2][ko4][par2][ch32][8]

  // A staging: wave wv stages m-group wv
  int rga = mc * 128 + wv * 32 + lo; rga = rga < Me ? rga : Me - 1;
  const __bf16* abase = xb + (size_t)rowtok[rs + rga] * EMBD + hi * 8;
  // B staging: thread -> (mat, k-octet, col-pair)
  int bm = t >> 7, ko = (t >> 5) & 3, np = t & 31;
  const float* bgb = (bm ? w1 : w0) + (size_t)e * EMBD * MLPD + nb + np * 2;
  int we0 = (((bm * 4 + ko) * 2 + 0) * 32 + np) * 8;   // parity-0 elem offset
  int we1 = (((bm * 4 + ko) * 2 + 1) * 32 + np) * 8;   // parity-1

  f32x2 vbS0[8], vbS1[8];
  f32x16 acc0[2], acc1[2];
  #pragma unroll
  for (int g = 0; g < 2; ++g)
    #pragma unroll
    for (int r = 0; r < 16; ++r) { acc0[g][r] = 0.f; acc1[g][r] = 0.f; }

  const int NT = EMBD / BKD;  // 32 (even)

#define LOADB1(VB, KS)                                                     \
  { int kkc = (KS) * BKD; kkc = kkc <= EMBD - BKD ? kkc : EMBD - BKD;      \
    _Pragma("unroll")                                                      \
    for (int q = 0; q < 8; ++q)                                            \
      VB[q] = *(const f32x2*)(bgb + (size_t)(kkc + ko * 8 + q) * MLPD); }
#define WRITEB1(VB, BUF)                                                   \
  { bf16x8 c0_, c1_;                                                       \
    _Pragma("unroll")                                                      \
    for (int q = 0; q < 8; ++q) { c0_[q] = (__bf16)VB[q][0]; c1_[q] = (__bf16)VB[q][1]; } \
    *(bf16x8*)&Bx[BUF][we0] = c0_;                                         \
    *(bf16x8*)&Bx[BUF][we1] = c1_; }
#define STAGEA1(KS, BUF)                                                   \
  { int kkc = (KS) * BKD; kkc = kkc <= EMBD - BKD ? kkc : EMBD - BKD;      \
    _Pragma("unroll")                                                      \
    for (int kh = 0; kh < 2; ++kh)                                         \
      gl16(abase + kkc + kh * 16, &Ax[BUF][(wv * 2 + kh) * 512]); }
#define COMPUTE1(BUF)                                                      \
  { bf16x8 av[2][2], bv0[2], bv1[2];                                       \
    _Pragma("unroll")                                                      \
    for (int g = 0; g < 2; ++g)                                            \
      _Pragma("unroll")                                                    \
      for (int kh = 0; kh < 2; ++kh)                                       \
        av[g][kh] = *(const bf16x8*)&Ax[BUF][((wr * 2 + g) * 2 + kh) * 512 + l * 8]; \
    _Pragma("unroll")                                                      \
    for (int kh = 0; kh < 2; ++kh) {                                       \
      int c_ = wc * 32 + lo;                                               \
      bv0[kh] = *(const bf16x8*)&Bx[BUF][(((0 * 4 + kh * 2 + hi) * 2 + (c_ & 1)) * 32 + (c_ >> 1)) * 8]; \
      bv1[kh] = *(const bf16x8*)&Bx[BUF][(((1 * 4 + kh * 2 + hi) * 2 + (c_ & 1)) * 32 + (c_ >> 1)) * 8]; \
    }                                                                      \
    _Pragma("unroll")                                                      \
    for (int kh = 0; kh < 2; ++kh)                                         \
      _Pragma("unroll")                                                    \
      for (int g = 0; g < 2; ++g) {                                        \
        acc0[g] = __builtin_amdgcn_mfma_f32_32x32x16_bf16(av[g][kh], bv0[kh], acc0[g], 0, 0, 0); \
        acc1[g] = __builtin_amdgcn_mfma_f32_32x32x16_bf16(av[g][kh], bv1[kh], acc1[g], 0, 0, 0); \
      } }
#define G1_ITER(J, VB, bA, bB, bC)                                         \
  { asm volatile("s_waitcnt vmcnt(10)" ::: "memory");                      \
    asm volatile("s_waitcnt lgkmcnt(0)" ::: "memory");                     \
    __builtin_amdgcn_sched_barrier(0);                                     \
    __builtin_amdgcn_s_barrier();                                          \
    if ((J) + 1 < NT) WRITEB1(VB, bB);                                     \
    __builtin_amdgcn_sched_barrier(0);                                     \
    LOADB1(VB, (J) + 3);                                                   \
    __builtin_amdgcn_sched_barrier(0);                                     \
    STAGEA1((J) + 2, bC);                                                  \
    __builtin_amdgcn_sched_barrier(0);                                     \
    COMPUTE1(bA); }

  // prologue: B(0)->set0->Bx[0]; B(1)->set1; A(0),A(1); B(2)->set0
  LOADB1(vbS0, 0);
  asm volatile("s_waitcnt vmcnt(0)" ::: "memory");
  WRITEB1(vbS0, 0);
  LOADB1(vbS1, 1);
  __builtin_amdgcn_sched_barrier(0);
  STAGEA1(0, 0);
  __builtin_amdgcn_sched_barrier(0);
  LOADB1(vbS0, 2);
  __builtin_amdgcn_sched_barrier(0);
  STAGEA1(1, 1);

  int bA = 0, bB = 1, bC = 2;
  for (int j = 0; j < NT; j += 2) {
    G1_ITER(j, vbS1, bA, bB, bC);
    { int tp = bA; bA = bB; bB = bC; bC = tp; }
    G1_ITER(j + 1, vbS0, bA, bB, bC);
    { int tp = bA; bA = bB; bB = bC; bC = tp; }
  }
  asm volatile("s_waitcnt vmcnt(0)" ::: "memory");
#undef G1_ITER
#undef COMPUTE1
#undef STAGEA1
#undef WRITEB1
#undef LOADB1

  // epilogue: silu(h0)*h1 -> bf16 inter. 32x32 C map: col=lo, row=(r&3)+8*(r>>2)+4*hi
  #pragma unroll
  for (int g = 0; g < 2; ++g)
    #pragma unroll
    for (int r = 0; r < 16; ++r) {
      int rl = mc * 128 + (wr * 2 + g) * 32 + (r & 3) + 8 * (r >> 2) + 4 * hi;
      if (rl < Me) {
        float h0 = acc0[g][r], h1 = acc1[g][r];
        float s = h0 / (1.f + expf(-h0)) * h1;
        inter[(size_t)(rs + rl) * MLPD + nb + wc * 32 + lo] = (__hip_bfloat16)s;
      }
    }
}

// ---------------- grouped GEMM 2: out_sorted = inter @ wo ----------------
// Same skeleton; single B matrix; vmcnt(6) (4 b64 + 2 gl16 per iter).
template <typename OS_T>
__global__ __launch_bounds__(256, 4) void gemm2_k(
    const __hip_bfloat16* __restrict__ inter, const float* __restrict__ wo,
    const int* __restrict__ counts, const int* __restrict__ base,
    OS_T* __restrict__ os) {
  int xr_ = blockIdx.x, zr_ = blockIdx.z;
  int xi = (xr_ & 8) | (zr_ & 7);
  int e  = (zr_ & ~7) | (xr_ & 7);
  int Me = counts[e];
  int mc = blockIdx.y;
  if (mc * 128 >= Me) return;
  int rs = base[e];
  int nb = xi * 64;
  int t = threadIdx.x;
  int wv = t >> 6, l = t & 63;
  int wr = wv >> 1, wc = wv & 1;
  int lo = l & 31, hi = l >> 5;

  __shared__ __bf16 Ax[3][4096];  // 3 x 8KB [g4][kh2][lane64][8]
  __shared__ __bf16 Bx[3][2048];  // 3 x 4KB [ko4][par2][ch32][8]

  int rga = mc * 128 + wv * 32 + lo; rga = rga < Me ? rga : Me - 1;
  const __bf16* abase = (const __bf16*)inter + (size_t)(rs + rga) * MLPD + hi * 8;
  int kq = t >> 5, np = t & 31;          // k-quad 0..7, col-pair 0..31
  const float* bgb = wo + (size_t)e * MLPD * EMBD + nb + np * 2;
  int o_ = kq >> 1, h2 = kq & 1;
  int we0 = ((o_ * 2 + 0) * 32 + np) * 8 + h2 * 4;
  int we1 = ((o_ * 2 + 1) * 32 + np) * 8 + h2 * 4;

  f32x2 vbS0[4], vbS1[4];
  f32x16 acc[2];
  #pragma unroll
  for (int g = 0; g < 2; ++g)
    #pragma unroll
    for (int r = 0; r < 16; ++r) acc[g][r] = 0.f;

  const int NT = MLPD / BKD;  // 64 (even)

#define LOADB2(VB, KS)                                                     \
  { int kkc = (KS) * BKD; kkc = kkc <= MLPD - BKD ? kkc : MLPD - BKD;      \
    _Pragma("unroll")                                                      \
    for (int q = 0; q < 4; ++q)                                            \
      VB[q] = *(const f32x2*)(bgb + (size_t)(kkc + kq * 4 + q) * EMBD); }
#define WRITEB2(VB, BUF)                                                   \
  { bf16x4 c0_, c1_;                                                       \
    _Pragma("unroll")                                                      \
    for (int q = 0; q < 4; ++q) { c0_[q] = (__bf16)VB[q][0]; c1_[q] = (__bf16)VB[q][1]; } \
    *(bf16x4*)&Bx[BUF][we0] = c0_;                                         \
    *(bf16x4*)&Bx[BUF][we1] = c1_; }
#define STAGEA2(KS, BUF)                                                   \
  { int kkc = (KS) * BKD; kkc = kkc <= MLPD - BKD ? kkc : MLPD - BKD;      \
    _Pragma("unroll")                                                      \
    for (int kh = 0; kh < 2; ++kh)                                         \
      gl16(abase + kkc + kh * 16, &Ax[BUF][(wv * 2 + kh) * 512]); }
#define COMPUTE2(BUF)                                                      \
  { bf16x8 av[2][2], bv[2];                                                \
    _Pragma("unroll")                                                      \
    for (int g = 0; g < 2; ++g)                                            \
      _Pragma("unroll")                                                    \
      for (int kh = 0; kh < 2; ++kh)                                       \
        av[g][kh] = *(const bf16x8*)&Ax[BUF][((wr * 2 + g) * 2 + kh) * 512 + l * 8]; \
    _Pragma("unroll")                                                      \
    for (int kh = 0; kh < 2; ++kh) {                                       \
      int c_ = wc * 32 + lo;                                               \
      bv[kh] = *(const bf16x8*)&Bx[BUF][(((kh * 2 + hi) * 2 + (c_ & 1)) * 32 + (c_ >> 1)) * 8]; \
    }                                                                      \
    _Pragma("unroll")                                                      \
    for (int kh = 0; kh < 2; ++kh)                                         \
      _Pragma("unroll")                                                    \
      for (int g = 0; g < 2; ++g)                                          \
        acc[g] = __builtin_amdgcn_mfma_f32_32x32x16_bf16(av[g][kh], bv[kh], acc[g], 0, 0, 0); }
#define G2_ITER(J, VB, bA, bB, bC)                                         \
  { asm volatile("s_waitcnt vmcnt(6)" ::: "memory");                       \
    asm volatile("s_waitcnt lgkmcnt(0)" ::: "memory");                     \
    __builtin_amdgcn_sched_barrier(0);                                     \
    __builtin_amdgcn_s_barrier();                                          \
    if ((J) + 1 < NT) WRITEB2(VB, bB);                                     \
    __builtin_amdgcn_sched_barrier(0);                                     \
    LOADB2(VB, (J) + 3);                                                   \
    __builtin_amdgcn_sched_barrier(0);                                     \
    STAGEA2((J) + 2, bC);                                                  \
    __builtin_amdgcn_sched_barrier(0);                                     \
    COMPUTE2(bA); }

  LOADB2(vbS0, 0);
  asm volatile("s_waitcnt vmcnt(0)" ::: "memory");
  WRITEB2(vbS0, 0);
  LOADB2(vbS1, 1);
  __builtin_amdgcn_sched_barrier(0);
  STAGEA2(0, 0);
  __builtin_amdgcn_sched_barrier(0);
  LOADB2(vbS0, 2);
  __builtin_amdgcn_sched_barrier(0);
  STAGEA2(1, 1);

  int bA = 0, bB = 1, bC = 2;
  for (int j = 0; j < NT; j += 2) {
    G2_ITER(j, vbS1, bA, bB, bC);
    { int tp = bA; bA = bB; bB = bC; bC = tp; }
    G2_ITER(j + 1, vbS0, bA, bB, bC);
    { int tp = bA; bA = bB; bB = bC; bC = tp; }
  }
  asm volatile("s_waitcnt vmcnt(0)" ::: "memory");
#undef G2_ITER
#undef COMPUTE2
#undef STAGEA2
#undef WRITEB2
#undef LOADB2

  #pragma unroll
  for (int g = 0; g < 2; ++g)
    #pragma unroll
    for (int r = 0; r < 16; ++r) {
      int rl = mc * 128 + (wr * 2 + g) * 32 + (r & 3) + 8 * (r >> 2) + 4 * hi;
      if (rl < Me)
        os[(size_t)(rs + rl) * EMBD + nb + wc * 32 + lo] = (OS_T)acc[g][r];
    }
}

// ---------------- combine: out[t] = w1*os[r1] + w2*os[r2] ----------------
template <typename OS_T>
__global__ __launch_bounds__(256) void combine_k(
    const OS_T* __restrict__ os, const int* __restrict__ f2r,
    const float* __restrict__ wf, float* __restrict__ out) {
  int t = blockIdx.x;
  int c = threadIdx.x * 4;
  int r0 = f2r[2 * t], r1 = f2r[2 * t + 1];
  float wa = wf[2 * t], wb = wf[2 * t + 1];
  const OS_T* pa = os + (size_t)r0 * EMBD + c;
  const OS_T* pb = os + (size_t)r1 * EMBD + c;
  float4 o;
  o.x = wa * (float)pa[0] + wb * (float)pb[0];
  o.y = wa * (float)pa[1] + wb * (float)pb[1];
  o.z = wa * (float)pa[2] + wb * (float)pb[2];
  o.w = wa * (float)pa[3] + wb * (float)pb[3];
  *(float4*)(out + (size_t)t * EMBD + c) = o;
}

// ---------------- launcher ----------------
extern "C" void kernel_launch(void* const* d_in, const int* in_sizes, int n_in,
                              void* d_out, int out_size, void* d_ws, size_t ws_size,
                              hipStream_t stream) {
  const float* x  = (const float*)d_in[0];
  const float* gk = (const float*)d_in[1];
  const float* w0 = (const float*)d_in[2];
  const float* w1 = (const float*)d_in[3];
  const float* wo = (const float*)d_in[4];
  float* out = (float*)d_out;
  char* ws = (char*)d_ws;

  int*   counts = (int*)(ws + OFF_COUNTS);
  int*   basep  = (int*)(ws + OFF_BASE);
  int*   run    = (int*)(ws + OFF_RUN);
  int*   ef     = (int*)(ws + OFF_EFLAT);
  float* wfl    = (float*)(ws + OFF_WFLAT);
  int*   rowtok = (int*)(ws + OFF_ROWTOK);
  int*   f2r    = (int*)(ws + OFF_F2R);
  __hip_bfloat16* inter = (__hip_bfloat16*)(ws + OFF_INTER);
  __bf16* xb = (__bf16*)(ws + OFF_XB);   // aliases os region (dead until gemm2)

  hipMemsetAsync(ws, 0, 1024, stream);
  cvt_x_k<<<NTOK * EMBD / (256 * 8), 256, 0, stream>>>(x, xb);
  router_topk<<<NTOK / 4, 256, 0, stream>>>(x, gk, ef, wfl);
  hist_k<<<NFLAT / 256, 256, 0, stream>>>(ef, counts);
  scan_k<<<1, 64, 0, stream>>>(counts, basep);
  scatter_k<<<NFLAT / 256, 256, 0, stream>>>(ef, basep, run, rowtok, f2r);
  gemm1_k<<<dim3(MLPD / 64, MAXCH, NEXP), 256, 0, stream>>>(xb, w0, w1, counts, basep, rowtok, inter);

  if (ws_size >= NEED_F32) {
    float* os = (float*)(ws + OFF_OS);
    gemm2_k<float><<<dim3(EMBD / 64, MAXCH, NEXP), 256, 0, stream>>>(inter, wo, counts, basep, os);
    combine_k<float><<<NTOK, 256, 0, stream>>>(os, f2r, wfl, out);
  } else {
    __hip_bfloat16* os = (__hip_bfloat16*)(ws + OFF_OS);
    gemm2_k<__hip_bfloat16><<<dim3(EMBD / 64, MAXCH, NEXP), 256, 0, stream>>>(inter, wo, counts, basep, os);
    combine_k<__hip_bfloat16><<<NTOK, 256, 0, stream>>>(os, f2r, wfl, out);
  }
}